// Round 13
// baseline (388.457 us; speedup 1.0000x reference)
//
#include <hip/hip_runtime.h>

#define N_ROWS 65536
#define D 256
#define K 1024
#define DECAYF 0.99f
#define OMDF 0.01f
#define EPSF 1e-5f
#define MARGIN 0.5f

typedef _Float16 f16;
typedef _Float16 f16x8 __attribute__((ext_vector_type(8)));
typedef float f32x16 __attribute__((ext_vector_type(16)));
typedef float f32x4 __attribute__((ext_vector_type(4)));

// ---------------- fused prep: zero dw/counts + codebook norms + hi-fp16 pack ----------------
// wsB granule g (16B), fields LSB->MSB: l31(5) cfg(2) sA(3) dk(2) cg(3)  [g < 32768]
// content: fp16(hi) of cb[cg*128+cfg*32+l31][dk*64 + sA*8 + e], e=0..7
__global__ __launch_bounds__(256) void prep_kernel(const float* __restrict__ cb,
                                                   float* __restrict__ cnorm,
                                                   char* __restrict__ wsB,
                                                   float* __restrict__ dw,
                                                   float* __restrict__ counts) {
    const int tid = threadIdx.x;
    const int bid = blockIdx.x;
    const int g = bid * 256 + tid;          // 0..65535
    *reinterpret_cast<float4*>(dw + (size_t)g * 4) = make_float4(0.f, 0.f, 0.f, 0.f);
    if (g < K) counts[g] = 0.f;
    {
        const int row = bid * 4 + (tid >> 6);
        const int lane = tid & 63;
        const float4 v = *reinterpret_cast<const float4*>(cb + (size_t)row * D + lane * 4);
        float s = v.x * v.x + v.y * v.y + v.z * v.z + v.w * v.w;
        #pragma unroll
        for (int m = 32; m; m >>= 1) s += __shfl_xor(s, m);
        if (lane == 0) cnorm[row] = s;
    }
    if (g < 32768) {
        const int l31 = g & 31;
        const int cfg = (g >> 5) & 3;
        const int sA  = (g >> 7) & 7;
        const int dk  = (g >> 10) & 3;
        const int cg  = g >> 12;            // 0..7
        const int code = cg * 128 + cfg * 32 + l31;
        const int dim0 = dk * 64 + sA * 8;
        const float* src = cb + (size_t)code * D + dim0;
        f16 out[8];
        #pragma unroll
        for (int e = 0; e < 8; ++e) out[e] = (f16)src[e];
        *reinterpret_cast<f16x8*>(wsB + (size_t)g * 16) = *reinterpret_cast<f16x8*>(out);
    }
}

// ---------------- coarse argmin v6b: A resident, B double-buffered with async prefetch ----------------
// block: 64 rows x 1024 codes, 256 thr = 4 waves (rw = wave>>1: 32-row half; cw = wave&1: 64-code half)
// 32 phases (cg 0..7 x dk 0..3); per phase per wave: 4 ks x 2 cf = 8 MFMA
// LDS: A 32KB | B0 16KB | B1 16KB | cand u16[64][16] | ccnt[64]   = 66.3 KB -> 2 blocks/CU
__global__ __launch_bounds__(256, 2) void argmin_coarse_kernel(
        const float* __restrict__ x, const float* __restrict__ cb,
        const char* __restrict__ wsB, const float* __restrict__ cnorm,
        int* __restrict__ idx_out, float* __restrict__ counts) {
    __shared__ char smem[67840];
    char* Alds = smem;                                          // 32768
    char* Bbuf0 = smem + 32768;                                 // 16384
    char* Bbuf1 = smem + 49152;                                 // 16384
    unsigned short* cand = reinterpret_cast<unsigned short*>(smem + 65536);  // [64][16]
    int* ccnt = reinterpret_cast<int*>(smem + 67584);           // [64]
    const int tid = threadIdx.x;
    const int wave = tid >> 6;
    const int lane = tid & 63;
    const int l31 = lane & 31;
    const int h = lane >> 5;
    const int rw = wave >> 1;
    const int cw = wave & 1;
    const int n0 = blockIdx.x * 64;

    if (tid < 64) ccnt[tid] = 0;

    // ---- prologue: stage A fully (64 rows x 256 dims hi-fp16, swizzled) + B tile 0 ----
    {
        const int s_row = tid >> 2;          // 0..63
        const int c4 = tid & 3;              // 64-dim chunk
        const float* src = x + (size_t)(n0 + s_row) * D + c4 * 64;
        char* rowbase = Alds + s_row * 512;
        const int sw = s_row & 7;
        #pragma unroll
        for (int j = 0; j < 8; ++j) {
            const float4 fa = *reinterpret_cast<const float4*>(src + j * 8);
            const float4 fb = *reinterpret_cast<const float4*>(src + j * 8 + 4);
            f16 h8[8] = {(f16)fa.x, (f16)fa.y, (f16)fa.z, (f16)fa.w,
                         (f16)fb.x, (f16)fb.y, (f16)fb.z, (f16)fb.w};
            const int ph = c4 * 8 + (j ^ sw);
            *reinterpret_cast<f16x8*>(rowbase + ph * 16) = *reinterpret_cast<f16x8*>(h8);
        }
        // B tile 0: 16KB = 1024 int4, 256 thr x 4 int4, stride 256
        const int4* gsrc = reinterpret_cast<const int4*>(wsB);
        int4* ldst = reinterpret_cast<int4*>(Bbuf0);
        #pragma unroll
        for (int i = 0; i < 4; ++i) ldst[tid + i * 256] = gsrc[tid + i * 256];
    }
    __syncthreads();

    const int arow = rw * 32 + l31;
    char* abase = Alds + arow * 512;
    const int asw = arow & 7;

    float B_run[16];
    #pragma unroll
    for (int r = 0; r < 16; ++r) B_run[r] = 3.4e38f;

    int cur = 0;
    #pragma unroll 1
    for (int cg = 0; cg < 8; ++cg) {
        f32x16 acc[2];
        #pragma unroll
        for (int cf = 0; cf < 2; ++cf)
            #pragma unroll
            for (int r = 0; r < 16; ++r) acc[cf][r] = 0.f;

        #pragma unroll 1
        for (int dk = 0; dk < 4; ++dk) {
            const int p = cg * 4 + dk;
            // issue next tile's global loads EARLY (latency hides under MFMA below)
            int4 pre0, pre1, pre2, pre3;
            if (p < 31) {
                const int4* gsrc = reinterpret_cast<const int4*>(wsB + (size_t)(p + 1) * 16384);
                pre0 = gsrc[tid];
                pre1 = gsrc[tid + 256];
                pre2 = gsrc[tid + 512];
                pre3 = gsrc[tid + 768];
            }
            // compute phase p from current buffer
            {
                const char* Bcur = cur ? Bbuf1 : Bbuf0;
                #pragma unroll
                for (int ks = 0; ks < 4; ++ks) {
                    const int sA = ks * 2 + h;
                    const f16x8 Ah = *reinterpret_cast<const f16x8*>(
                        abase + (dk * 8 + (sA ^ asw)) * 16);
                    #pragma unroll
                    for (int cf = 0; cf < 2; ++cf) {
                        const f16x8 Bh = *reinterpret_cast<const f16x8*>(
                            Bcur + ((sA * 4 + cw * 2 + cf) * 32 + l31) * 16);
                        acc[cf] = __builtin_amdgcn_mfma_f32_32x32x16_f16(Ah, Bh, acc[cf], 0, 0, 0);
                    }
                }
            }
            // land the prefetch into the other buffer
            if (p < 31) {
                int4* ldst = reinterpret_cast<int4*>(cur ? Bbuf0 : Bbuf1);
                ldst[tid] = pre0;
                ldst[tid + 256] = pre1;
                ldst[tid + 512] = pre2;
                ldst[tid + 768] = pre3;
            }
            // fold this cg after its last dk (registers + cand LDS only)
            if (dk == 3) {
                const int codebase = cg * 128 + cw * 64;
                const float cn0 = cnorm[codebase + l31];
                const float cn1 = cnorm[codebase + 32 + l31];
                #pragma unroll
                for (int r = 0; r < 16; ++r) {
                    const float d0 = cn0 - 2.f * acc[0][r];
                    const float d1 = cn1 - 2.f * acc[1][r];
                    float m = fminf(d0, d1);
                    #pragma unroll
                    for (int msk = 16; msk; msk >>= 1) m = fminf(m, __shfl_xor(m, msk));
                    const float br = fminf(B_run[r], m);
                    B_run[r] = br;
                    const float lim = br + MARGIN;
                    const int row = rw * 32 + (r & 3) + 8 * (r >> 2) + 4 * h;
                    if (d0 <= lim) {
                        const int pos = atomicAdd(&ccnt[row], 1);
                        if (pos < 16) cand[row * 16 + pos] = (unsigned short)(codebase + l31);
                    }
                    if (d1 <= lim) {
                        const int pos = atomicAdd(&ccnt[row], 1);
                        if (pos < 16) cand[row * 16 + pos] = (unsigned short)(codebase + 32 + l31);
                    }
                }
            }
            __syncthreads();
            cur ^= 1;
        }
    }
    // ---- exact fp32 refine: wave w handles rows w*16..w*16+15 ----
    #pragma unroll 1
    for (int rr = 0; rr < 16; ++rr) {
        const int row = wave * 16 + rr;
        const int n = ccnt[row];
        const f32x4 xv = *reinterpret_cast<const f32x4*>(x + (size_t)(n0 + row) * D + lane * 4);
        float bd = 3.4e38f;
        int bi = K;
        if (n <= 16) {
            for (int j = 0; j < n; ++j) {
                const int code = cand[row * 16 + j];
                const f32x4 cv = *reinterpret_cast<const f32x4*>(cb + (size_t)code * D + lane * 4);
                float s = xv[0] * cv[0] + xv[1] * cv[1] + xv[2] * cv[2] + xv[3] * cv[3];
                #pragma unroll
                for (int msk = 32; msk; msk >>= 1) s += __shfl_xor(s, msk);
                const float dd = cnorm[code] - 2.f * s;
                if (dd < bd || (dd == bd && code < bi)) { bd = dd; bi = code; }
            }
        } else {
            for (int code = 0; code < K; ++code) {
                const f32x4 cv = *reinterpret_cast<const f32x4*>(cb + (size_t)code * D + lane * 4);
                float s = xv[0] * cv[0] + xv[1] * cv[1] + xv[2] * cv[2] + xv[3] * cv[3];
                #pragma unroll
                for (int msk = 32; msk; msk >>= 1) s += __shfl_xor(s, msk);
                const float dd = cnorm[code] - 2.f * s;
                if (dd < bd) { bd = dd; bi = code; }
            }
        }
        if (lane == 0) {
            idx_out[n0 + row] = bi;
            atomicAdd(&counts[bi], 1.0f);
        }
    }
}

// ---------------- quantized gather (nontemporal stores) ----------------
__global__ __launch_bounds__(256) void quant_kernel(const float* __restrict__ cb,
                                                    const int* __restrict__ idx,
                                                    float* __restrict__ quant) {
    const int n = blockIdx.x * 4 + (threadIdx.x >> 6);
    const int lane = threadIdx.x & 63;
    const int i = idx[n];
    const f32x4 c = *reinterpret_cast<const f32x4*>(cb + (size_t)i * D + lane * 4);
    __builtin_nontemporal_store(c, reinterpret_cast<f32x4*>(quant + (size_t)n * D + lane * 4));
}

// ---------------- one-hot encodings (nontemporal stores) ----------------
__global__ __launch_bounds__(256) void enc_kernel(const int* __restrict__ idx,
                                                  float* __restrict__ enc) {
    const int total = N_ROWS * (K / 4);
    for (int g = blockIdx.x * blockDim.x + threadIdx.x; g < total;
         g += gridDim.x * blockDim.x) {
        const int n = g >> 8;
        const int k0 = (g & 255) * 4;
        const int i = idx[n];
        f32x4 v;
        v[0] = (k0 == i) ? 1.f : 0.f;
        v[1] = (k0 + 1 == i) ? 1.f : 0.f;
        v[2] = (k0 + 2 == i) ? 1.f : 0.f;
        v[3] = (k0 + 3 == i) ? 1.f : 0.f;
        __builtin_nontemporal_store(v, reinterpret_cast<f32x4*>(enc + (size_t)g * 4));
    }
}

// ---------------- cs EMA + Laplace + exclusive scan (wave-scan) ----------------
__global__ __launch_bounds__(1024) void cs_scan_kernel(const float* __restrict__ ema_cs,
                                                       const float* __restrict__ counts,
                                                       float* __restrict__ cs_out,
                                                       int* __restrict__ cursor) {
    __shared__ float wsum[16];
    __shared__ int wisum[16];
    __shared__ float n_sh;
    const int k = threadIdx.x;
    const int wid = k >> 6;
    const int lane = k & 63;
    const float cnt = counts[k];
    const float c = ema_cs[k] * DECAYF + OMDF * cnt;
    const int ic = (int)cnt;
    int v = ic;
    #pragma unroll
    for (int d = 1; d < 64; d <<= 1) {
        const int t = __shfl_up(v, d);
        if (lane >= d) v += t;
    }
    float s = c;
    #pragma unroll
    for (int m = 32; m; m >>= 1) s += __shfl_xor(s, m);
    if (lane == 63) wisum[wid] = v;
    if (lane == 0) wsum[wid] = s;
    __syncthreads();
    if (k == 0) {
        float n = 0.f;
        for (int w = 0; w < 16; ++w) n += wsum[w];
        n_sh = n;
    }
    if (wid == 0 && lane < 16) {
        int wv = wisum[lane];
        #pragma unroll
        for (int d = 1; d < 16; d <<= 1) {
            const int t = __shfl_up(wv, d);
            if (lane >= d) wv += t;
        }
        wisum[lane] = wv;
    }
    __syncthreads();
    const float n = n_sh;
    cs_out[k] = (c + EPSF) / (n + c * EPSF) * n;
    const int wbase = (wid == 0) ? 0 : wisum[wid - 1];
    cursor[k] = wbase + v - ic;
}

// ---------------- scatter rows by code, block-aggregated ----------------
__global__ __launch_bounds__(256) void scatter_kernel(const int* __restrict__ idx,
                                                      int* __restrict__ cursor,
                                                      int* __restrict__ rowlist,
                                                      int* __restrict__ codelist) {
    __shared__ int hist[1024];
    const int tid = threadIdx.x;
    #pragma unroll
    for (int j = 0; j < 4; ++j) hist[tid + j * 256] = 0;
    __syncthreads();
    const int n = blockIdx.x * 256 + tid;
    const int i = idx[n];
    atomicAdd(&hist[i], 1);
    __syncthreads();
    #pragma unroll
    for (int j = 0; j < 4; ++j) {
        const int k = tid + j * 256;
        const int c = hist[k];
        hist[k] = (c > 0) ? atomicAdd(&cursor[k], c) : 0;
    }
    __syncthreads();
    const int pos = atomicAdd(&hist[i], 1);
    rowlist[pos] = n;
    codelist[pos] = i;
}

// ---------------- balanced segmented sum over sorted rowlist ----------------
__global__ __launch_bounds__(256) void chunk_sum_kernel(const float* __restrict__ x,
                                                        const int* __restrict__ rowlist,
                                                        const int* __restrict__ codelist,
                                                        float* __restrict__ dw) {
    const int wave = threadIdx.x >> 6;
    const int lane = threadIdx.x & 63;
    const int p0 = blockIdx.x * 32 + wave * 8;
    int rows[8], codes[8];
    #pragma unroll
    for (int j = 0; j < 8; ++j) {
        rows[j] = rowlist[p0 + j];
        codes[j] = codelist[p0 + j];
    }
    f32x4 v[8];
    #pragma unroll
    for (int j = 0; j < 8; ++j)
        v[j] = __builtin_nontemporal_load(
            reinterpret_cast<const f32x4*>(x + (size_t)rows[j] * D + lane * 4));
    f32x4 s = v[0];
    int cur = codes[0];
    #pragma unroll
    for (int j = 1; j < 8; ++j) {
        if (codes[j] != cur) {
            float* dst = dw + (size_t)cur * D + lane * 4;
            atomicAdd(dst + 0, s[0]); atomicAdd(dst + 1, s[1]);
            atomicAdd(dst + 2, s[2]); atomicAdd(dst + 3, s[3]);
            cur = codes[j];
            s = v[j];
        } else {
            s[0] += v[j][0]; s[1] += v[j][1]; s[2] += v[j][2]; s[3] += v[j][3];
        }
    }
    float* dst = dw + (size_t)cur * D + lane * 4;
    atomicAdd(dst + 0, s[0]); atomicAdd(dst + 1, s[1]);
    atomicAdd(dst + 2, s[2]); atomicAdd(dst + 3, s[3]);
}

// ---------------- ema_w + new codebook ----------------
__global__ __launch_bounds__(256) void ema_kernel(const float* __restrict__ ema_w,
                                                  const float* __restrict__ dw,
                                                  const float* __restrict__ cs,
                                                  float* __restrict__ w_out,
                                                  float* __restrict__ cb_out) {
    const int e4 = blockIdx.x * blockDim.x + threadIdx.x;
    const int k = e4 >> 6;
    const float csk = cs[k];
    const float4 w = *reinterpret_cast<const float4*>(ema_w + (size_t)e4 * 4);
    const float4 d = *reinterpret_cast<const float4*>(dw + (size_t)e4 * 4);
    float4 nw, nc;
    nw.x = w.x * DECAYF + OMDF * d.x;
    nw.y = w.y * DECAYF + OMDF * d.y;
    nw.z = w.z * DECAYF + OMDF * d.z;
    nw.w = w.w * DECAYF + OMDF * d.w;
    nc.x = nw.x / csk; nc.y = nw.y / csk; nc.z = nw.z / csk; nc.w = nw.w / csk;
    *reinterpret_cast<float4*>(w_out + (size_t)e4 * 4) = nw;
    *reinterpret_cast<float4*>(cb_out + (size_t)e4 * 4) = nc;
}

extern "C" void kernel_launch(void* const* d_in, const int* in_sizes, int n_in,
                              void* d_out, int out_size, void* d_ws, size_t ws_size,
                              hipStream_t stream) {
    (void)in_sizes; (void)n_in; (void)out_size; (void)ws_size;
    const float* x      = (const float*)d_in[0];
    const float* cb     = (const float*)d_in[1];
    const float* ema_w  = (const float*)d_in[2];
    const float* ema_cs = (const float*)d_in[3];

    float* out    = (float*)d_out;
    float* quant  = out;
    float* enc    = quant + 16777216;
    float* cs_out = enc + 67108864;
    float* w_out  = cs_out + 1024;
    float* cb_out = w_out + 262144;

    float* ws       = (float*)d_ws;
    float* counts   = ws;                          // 1024 f
    float* dw       = ws + 1024;                   // 262144 f
    float* cnorm    = ws + 263168;                 // 1024 f
    int*   cursor   = (int*)(ws + 264192);         // 1024 i
    int*   idx      = (int*)(ws + 265216);         // 65536 i
    int*   rowlist  = (int*)(ws + 330752);         // 65536 i
    int*   codelist = (int*)(ws + 396288);         // 65536 i
    char*  wsB      = (char*)(ws + 461824);        // 512 KiB, 16B aligned

    prep_kernel<<<256, 256, 0, stream>>>(cb, cnorm, wsB, dw, counts);
    argmin_coarse_kernel<<<N_ROWS / 64, 256, 0, stream>>>(x, cb, wsB, cnorm, idx, counts);
    quant_kernel<<<N_ROWS / 4, 256, 0, stream>>>(cb, idx, quant);
    enc_kernel<<<2048, 256, 0, stream>>>(idx, enc);
    cs_scan_kernel<<<1, 1024, 0, stream>>>(ema_cs, counts, cs_out, cursor);
    scatter_kernel<<<N_ROWS / 256, 256, 0, stream>>>(idx, cursor, rowlist, codelist);
    chunk_sum_kernel<<<2048, 256, 0, stream>>>(x, rowlist, codelist, dw);
    ema_kernel<<<65536 / 256, 256, 0, stream>>>(ema_w, dw, cs_out, w_out, cb_out);
}